// Round 3
// baseline (140.878 us; speedup 1.0000x reference)
//
#include <hip/hip_runtime.h>
#include <math.h>

#define N_TOK 8192
#define DIM   1024
#define NE    8
#define NR    16
#define NO    3072
#define OUT_ELEMS (N_TOK * NO)   // 25165824

__device__ __forceinline__ float softplusf(float z) {
  return z > 0.f ? z + log1pf(expf(-z)) : log1pf(expf(z));
}
__device__ __forceinline__ float ncdf(float z) {
  return 0.5f * erfcf(-z * 0.70710678118654752f);
}

#define FMA4(A, S, W) { (A).x = fmaf((S),(W).x,(A).x); (A).y = fmaf((S),(W).y,(A).y); \
                        (A).z = fmaf((S),(W).z,(A).z); (A).w = fmaf((S),(W).w,(A).w); }
#define RED4(A, OFF) { (A).x += __shfl_xor((A).x, OFF); (A).y += __shfl_xor((A).y, OFF); \
                       (A).z += __shfl_xor((A).z, OFF); (A).w += __shfl_xor((A).w, OFF); }
#define Z4 make_float4(0.f,0.f,0.f,0.f)

// ---------------------------------------------------------------------------
// Kernel A: gating GEMV with weights held in registers.
// Block = 16 tokens; wave w owns d in [256w,256w+256); lane owns 4 d.
// Preload (once): wg/wn rows for lane's 4 d -> 16 float4 VGPRs.
// Per token: 1 prefetched x float4 load + 64 FMA + 96-shfl butterfly.
// ---------------------------------------------------------------------------
__global__ __launch_bounds__(256) void kA(const float* __restrict__ x,
    const float* __restrict__ wg, const float* __restrict__ wn,
    const float* __restrict__ nz, int* __restrict__ eid, float* __restrict__ part) {
  __shared__ float pSh[4][16][16];    // [wave][token][output]
  int t = threadIdx.x;
  int wid = t >> 6, lane = t & 63;
  int nb0 = blockIdx.x << 4;
  int dbase = (wid << 8) + (lane << 2);
  // weight preload: for local d j=0..3, gate outputs 0-3/4-7 and noise 0-3/4-7
  const float* wgp = wg + (size_t)dbase * NE;
  const float* wnp = wn + (size_t)dbase * NE;
  float4 g0a = *(const float4*)(wgp + 0),  g0b = *(const float4*)(wgp + 4);
  float4 g1a = *(const float4*)(wgp + 8),  g1b = *(const float4*)(wgp + 12);
  float4 g2a = *(const float4*)(wgp + 16), g2b = *(const float4*)(wgp + 20);
  float4 g3a = *(const float4*)(wgp + 24), g3b = *(const float4*)(wgp + 28);
  float4 q0a = *(const float4*)(wnp + 0),  q0b = *(const float4*)(wnp + 4);
  float4 q1a = *(const float4*)(wnp + 8),  q1b = *(const float4*)(wnp + 12);
  float4 q2a = *(const float4*)(wnp + 16), q2b = *(const float4*)(wnp + 20);
  float4 q3a = *(const float4*)(wnp + 24), q3b = *(const float4*)(wnp + 28);
  const float* xb = x + (size_t)nb0 * DIM + dbase;
  float4 xv = *(const float4*)(xb);
  #pragma unroll 4
  for (int tok = 0; tok < 16; ++tok) {
    float4 xn = *(const float4*)(xb + (size_t)((tok + 1) & 15) * DIM);  // prefetch
    float4 aA = Z4, aB = Z4, aC = Z4, aD = Z4;  // gate 0-3, 4-7; noise 0-3, 4-7
    FMA4(aA, xv.x, g0a); FMA4(aB, xv.x, g0b); FMA4(aC, xv.x, q0a); FMA4(aD, xv.x, q0b);
    FMA4(aA, xv.y, g1a); FMA4(aB, xv.y, g1b); FMA4(aC, xv.y, q1a); FMA4(aD, xv.y, q1b);
    FMA4(aA, xv.z, g2a); FMA4(aB, xv.z, g2b); FMA4(aC, xv.z, q2a); FMA4(aD, xv.z, q2b);
    FMA4(aA, xv.w, g3a); FMA4(aB, xv.w, g3b); FMA4(aC, xv.w, q3a); FMA4(aD, xv.w, q3b);
    #pragma unroll
    for (int off = 1; off <= 32; off <<= 1) {
      RED4(aA, off); RED4(aB, off); RED4(aC, off); RED4(aD, off);
    }
    if (lane == 0) {
      *(float4*)&pSh[wid][tok][0]  = aA;
      *(float4*)&pSh[wid][tok][4]  = aB;
      *(float4*)&pSh[wid][tok][8]  = aC;
      *(float4*)&pSh[wid][tok][12] = aD;
    }
    xv = xn;
  }
  __syncthreads();
  if (t < 16) {
    int n = nb0 + t;
    float cl[8], st[8], lg[8];
    #pragma unroll
    for (int e = 0; e < 8; ++e)
      cl[e] = pSh[0][t][e] + pSh[1][t][e] + pSh[2][t][e] + pSh[3][t][e];
    #pragma unroll
    for (int e = 0; e < 8; ++e) {
      float raw = pSh[0][t][8+e] + pSh[1][t][8+e] + pSh[2][t][8+e] + pSh[3][t][8+e];
      st[e] = softplusf(raw) + 0.01f;
      lg[e] = fmaf(nz[(size_t)n * NE + e], st[e], cl[e]);
    }
    float m1 = -1e30f, m2 = -1e30f; int idx = 0;
    #pragma unroll
    for (int e = 0; e < 8; ++e) {
      float v = lg[e];
      if (v > m1)      { m2 = m1; m1 = v; idx = e; }
      else if (v > m2) { m2 = v; }
    }
    eid[n] = idx;
    float pr[8], cw[8];
    #pragma unroll
    for (int e = 0; e < 8; ++e) {
      float thr = (lg[e] > m2) ? m2 : m1;
      pr[e] = ncdf((cl[e] - thr) / st[e]);
    }
    #pragma unroll
    for (int e = 0; e < 8; ++e) cw[e] = (float)__popcll(__ballot(idx == e));
    #pragma unroll
    for (int e = 0; e < 8; ++e) {
      #pragma unroll
      for (int off = 1; off <= 8; off <<= 1) pr[e] += __shfl_xor(pr[e], off);
    }
    if (t == 0) {
      #pragma unroll
      for (int e = 0; e < 8; ++e) {
        part[blockIdx.x * 16 + e]     = cw[e];
        part[blockIdx.x * 16 + 8 + e] = pr[e];
      }
    }
  }
}

// ---------------------------------------------------------------------------
// Kernel B: reduce 512x16 partials -> importance[8], load[8]; counts; fill=0.
// ---------------------------------------------------------------------------
__global__ __launch_bounds__(256) void kB(const float* __restrict__ part,
    float* __restrict__ outIL, int* __restrict__ counts, int* __restrict__ fill) {
  __shared__ float red[16][16];
  int t = threadIdx.x;
  int s = t & 15, g = t >> 4;
  float sum = 0.f;
  for (int j = 0; j < 32; ++j) sum += part[(g + 16 * j) * 16 + s];
  red[g][s] = sum;
  __syncthreads();
  if (t < 16) {
    float tot = 0.f;
    #pragma unroll
    for (int gg = 0; gg < 16; ++gg) tot += red[gg][t];
    outIL[t] = tot;
    if (t < 8) { counts[t] = (int)(tot + 0.5f); fill[t] = 0; }
  }
}

// ---------------------------------------------------------------------------
// Kernel C: bucket tokens by expert (LDS hist + 8 global atomics per block).
// ---------------------------------------------------------------------------
__global__ __launch_bounds__(256) void kC(const int* __restrict__ eid,
    const int* __restrict__ counts, int* __restrict__ fill, int* __restrict__ bucket) {
  __shared__ int lcnt[8], lbase[8];
  int t = threadIdx.x;
  if (t < 8) lcnt[t] = 0;
  __syncthreads();
  int n = blockIdx.x * 256 + t;
  int e = eid[n];
  int rank = atomicAdd(&lcnt[e], 1);
  __syncthreads();
  if (t < 8) lbase[t] = atomicAdd(&fill[t], lcnt[t]);
  __syncthreads();
  int off = 0;
  #pragma unroll
  for (int i = 0; i < 8; ++i) if (i < e) off += counts[i];
  bucket[off + lbase[e] + rank] = n;
}

// ---------------------------------------------------------------------------
// Kernel D: h_sorted[p] = lora_a[e] @ x[bucket[p]], 16 tokens/tile.
// Same register-resident weight structure as kA: wave owns 256 d, lane 4 d,
// 16 r-rows preloaded as 16 float4 VGPRs (coalesced, la is [e][r][d]).
// ---------------------------------------------------------------------------
__global__ __launch_bounds__(256) void kD(const float* __restrict__ x,
    const float* __restrict__ la, const int* __restrict__ counts,
    const int* __restrict__ bucket, float* __restrict__ h) {
  __shared__ float pSh[4][16][16];
  __shared__ int toks[16];
  int tile = blockIdx.x;
  int e = -1, jt = 0, off = 0;
  { int tot = 0, o = 0;
    #pragma unroll
    for (int i = 0; i < 8; ++i) {
      int c = counts[i]; int nt = (c + 15) >> 4;
      if (e < 0 && tile < tot + nt) { e = i; jt = tile - tot; off = o; }
      tot += nt; o += c;
    } }
  if (e < 0) return;
  int cnt = counts[e];
  int p0 = off + (jt << 4);
  int valid = min(16, cnt - (jt << 4));
  int t = threadIdx.x;
  if (t < 16) toks[t] = bucket[p0 + min(t, valid - 1)];
  __syncthreads();
  int wid = t >> 6, lane = t & 63;
  int dbase = (wid << 8) + (lane << 2);
  const float* ap = la + (size_t)e * NR * DIM + dbase;
  float4 w0  = *(const float4*)(ap + 0  * DIM), w1  = *(const float4*)(ap + 1  * DIM);
  float4 w2  = *(const float4*)(ap + 2  * DIM), w3  = *(const float4*)(ap + 3  * DIM);
  float4 w4  = *(const float4*)(ap + 4  * DIM), w5  = *(const float4*)(ap + 5  * DIM);
  float4 w6  = *(const float4*)(ap + 6  * DIM), w7  = *(const float4*)(ap + 7  * DIM);
  float4 w8  = *(const float4*)(ap + 8  * DIM), w9  = *(const float4*)(ap + 9  * DIM);
  float4 w10 = *(const float4*)(ap + 10 * DIM), w11 = *(const float4*)(ap + 11 * DIM);
  float4 w12 = *(const float4*)(ap + 12 * DIM), w13 = *(const float4*)(ap + 13 * DIM);
  float4 w14 = *(const float4*)(ap + 14 * DIM), w15 = *(const float4*)(ap + 15 * DIM);
  float4 xv = *(const float4*)(x + (size_t)toks[0] * DIM + dbase);
  #pragma unroll 4
  for (int tok = 0; tok < 16; ++tok) {
    float4 xn = *(const float4*)(x + (size_t)toks[(tok + 1) & 15] * DIM + dbase);
    float4 aA = Z4, aB = Z4, aC = Z4, aD = Z4;
    #define DOTC(ACC, W) ACC = fmaf(xv.x,(W).x, fmaf(xv.y,(W).y, fmaf(xv.z,(W).z, fmaf(xv.w,(W).w,(ACC)))))
    DOTC(aA.x, w0);  DOTC(aA.y, w1);  DOTC(aA.z, w2);  DOTC(aA.w, w3);
    DOTC(aB.x, w4);  DOTC(aB.y, w5);  DOTC(aB.z, w6);  DOTC(aB.w, w7);
    DOTC(aC.x, w8);  DOTC(aC.y, w9);  DOTC(aC.z, w10); DOTC(aC.w, w11);
    DOTC(aD.x, w12); DOTC(aD.y, w13); DOTC(aD.z, w14); DOTC(aD.w, w15);
    #undef DOTC
    #pragma unroll
    for (int of = 1; of <= 32; of <<= 1) {
      RED4(aA, of); RED4(aB, of); RED4(aC, of); RED4(aD, of);
    }
    if (lane == 0) {
      *(float4*)&pSh[wid][tok][0]  = aA;
      *(float4*)&pSh[wid][tok][4]  = aB;
      *(float4*)&pSh[wid][tok][8]  = aC;
      *(float4*)&pSh[wid][tok][12] = aD;
    }
    xv = xn;
  }
  __syncthreads();
  if (t < 16 && t < valid) {
    float hv[16];
    #pragma unroll
    for (int r = 0; r < 16; ++r)
      hv[r] = pSh[0][t][r] + pSh[1][t][r] + pSh[2][t][r] + pSh[3][t][r];
    float* hp = h + (size_t)(p0 + t) * NR;
    *(float4*)(hp + 0)  = make_float4(hv[0], hv[1], hv[2], hv[3]);
    *(float4*)(hp + 4)  = make_float4(hv[4], hv[5], hv[6], hv[7]);
    *(float4*)(hp + 8)  = make_float4(hv[8], hv[9], hv[10], hv[11]);
    *(float4*)(hp + 12) = make_float4(hv[12], hv[13], hv[14], hv[15]);
  }
}

// ---------------------------------------------------------------------------
// Kernel E: out[n] = lora_b[e] @ h. Tiles: 64 tokens x 256 outs.
// ---------------------------------------------------------------------------
__global__ __launch_bounds__(256) void kE(const float* __restrict__ h,
    const float* __restrict__ lb, const int* __restrict__ counts,
    const int* __restrict__ bucket, float* __restrict__ out) {
  __shared__ float bt[16][260];
  __shared__ float ht[16][64];
  __shared__ int toks[64];
  int tile = blockIdx.y;
  int e = -1, jt = 0, off = 0;
  { int tot = 0, o = 0;
    #pragma unroll
    for (int i = 0; i < 8; ++i) {
      int c = counts[i]; int nt = (c + 63) >> 6;
      if (e < 0 && tile < tot + nt) { e = i; jt = tile - tot; off = o; }
      tot += nt; o += c;
    } }
  if (e < 0) return;
  int cnt = counts[e];
  int p0 = off + (jt << 6);
  int valid = min(64, cnt - (jt << 6));
  int o0 = blockIdx.x << 8;
  int t = threadIdx.x;
  if (t < 64) toks[t] = bucket[p0 + min(t, valid - 1)];
  const float* bbase = lb + ((size_t)e * NO + o0) * NR;
  #pragma unroll
  for (int kk = 0; kk < 4; ++kk) {
    int idx = (kk << 8) + t;
    int o = idx >> 2, rq = (idx & 3) << 2;
    float4 v = *(const float4*)(bbase + o * NR + rq);
    bt[rq + 0][o] = v.x; bt[rq + 1][o] = v.y; bt[rq + 2][o] = v.z; bt[rq + 3][o] = v.w;
  }
  { int tok = t >> 2, rq = (t & 3) << 2;
    float4 v = *(const float4*)(h + (size_t)(p0 + min(tok, valid - 1)) * NR + rq);
    ht[rq + 0][tok] = v.x; ht[rq + 1][tok] = v.y; ht[rq + 2][tok] = v.z; ht[rq + 3][tok] = v.w; }
  __syncthreads();
  int og = t & 31, tokg = t >> 5;
  int ob = og << 2, tb = tokg << 3;
  float4 z = Z4;
  float4 aL0=z,aL1=z,aL2=z,aL3=z,aL4=z,aL5=z,aL6=z,aL7=z;
  float4 aH0=z,aH1=z,aH2=z,aH3=z,aH4=z,aH5=z,aH6=z,aH7=z;
  #pragma unroll
  for (int r = 0; r < 16; ++r) {
    float4 blo = *(const float4*)&bt[r][ob];
    float4 bhi = *(const float4*)&bt[r][ob + 128];
    float4 h0  = *(const float4*)&ht[r][tb];
    float4 h1  = *(const float4*)&ht[r][tb + 4];
    FMA4(aL0, h0.x, blo); FMA4(aH0, h0.x, bhi);
    FMA4(aL1, h0.y, blo); FMA4(aH1, h0.y, bhi);
    FMA4(aL2, h0.z, blo); FMA4(aH2, h0.z, bhi);
    FMA4(aL3, h0.w, blo); FMA4(aH3, h0.w, bhi);
    FMA4(aL4, h1.x, blo); FMA4(aH4, h1.x, bhi);
    FMA4(aL5, h1.y, blo); FMA4(aH5, h1.y, bhi);
    FMA4(aL6, h1.z, blo); FMA4(aH6, h1.z, bhi);
    FMA4(aL7, h1.w, blo); FMA4(aH7, h1.w, bhi);
  }
  #define ST(J, AL, AH) { int tt = tb + (J); if (tt < valid) { \
      float* p = out + (size_t)toks[tt] * NO + o0 + ob; \
      *(float4*)p = AL; *(float4*)(p + 128) = AH; } }
  ST(0, aL0, aH0); ST(1, aL1, aH1); ST(2, aL2, aH2); ST(3, aL3, aH3);
  ST(4, aL4, aH4); ST(5, aL5, aH5); ST(6, aL6, aH6); ST(7, aL7, aH7);
  #undef ST
}

// ---------------------------------------------------------------------------
extern "C" void kernel_launch(void* const* d_in, const int* in_sizes, int n_in,
                              void* d_out, int out_size, void* d_ws, size_t ws_size,
                              hipStream_t stream) {
  const float* x  = (const float*)d_in[0];
  const float* wg = (const float*)d_in[1];
  const float* wn = (const float*)d_in[2];
  const float* la = (const float*)d_in[3];
  const float* lb = (const float*)d_in[4];
  const float* nz = (const float*)d_in[5];
  float* out = (float*)d_out;

  char* ws = (char*)d_ws;
  float* h        = (float*)(ws);                 // 524288 B
  int*   eid      = (int*)  (ws + 524288);        // 32768 B
  int*   bucket   = (int*)  (ws + 557056);        // 32768 B
  float* partials = (float*)(ws + 589824);        // 32768 B
  int*   counts   = (int*)  (ws + 622592);        // 32 B
  int*   fill     = (int*)  (ws + 622624);        // 32 B

  kA<<<512, 256, 0, stream>>>(x, wg, wn, nz, eid, partials);
  kB<<<1, 256, 0, stream>>>(partials, out + OUT_ELEMS, counts, fill);
  kC<<<32, 256, 0, stream>>>(eid, counts, fill, bucket);
  kD<<<519, 256, 0, stream>>>(x, la, counts, bucket, h);
  kE<<<dim3(12, 135), 256, 0, stream>>>(h, lb, counts, bucket, out);
}

// Round 4
// 77.528 us; speedup vs baseline: 1.8171x; 1.8171x over previous
//
#include <hip/hip_runtime.h>
#include <math.h>

#define N_TOK 8192
#define DIM   1024
#define NE    8
#define NR    16
#define NO    3072
#define OUT_ELEMS (N_TOK * NO)   // 25165824

__device__ __forceinline__ float softplusf(float z) {
  return z > 0.f ? z + log1pf(expf(-z)) : log1pf(expf(z));
}
__device__ __forceinline__ float ncdf(float z) {
  return 0.5f * erfcf(-z * 0.70710678118654752f);
}

#define FMA4(A, S, W) { (A).x = fmaf((S),(W).x,(A).x); (A).y = fmaf((S),(W).y,(A).y); \
                        (A).z = fmaf((S),(W).z,(A).z); (A).w = fmaf((S),(W).w,(A).w); }
#define Z4 make_float4(0.f,0.f,0.f,0.f)

// quad-level cross-lane add via DPP (VALU pipe, no LDS):
// xor1 = quad_perm[1,0,3,2] = 0xB1 ; xor2 = quad_perm[2,3,0,1] = 0x4E
#define DPP_ADD(V, CTRL) ((V) + __int_as_float(__builtin_amdgcn_update_dpp(0, __float_as_int(V), (CTRL), 0xf, 0xf, true)))
#define QRED4(A) { (A).x = DPP_ADD((A).x, 0xB1); (A).y = DPP_ADD((A).y, 0xB1); \
                   (A).z = DPP_ADD((A).z, 0xB1); (A).w = DPP_ADD((A).w, 0xB1); \
                   (A).x = DPP_ADD((A).x, 0x4E); (A).y = DPP_ADD((A).y, 0x4E); \
                   (A).z = DPP_ADD((A).z, 0x4E); (A).w = DPP_ADD((A).w, 0x4E); }

// ---------------------------------------------------------------------------
// Kernel A: gating GEMV. 16 tokens/block; thread t owns d = [4t, 4t+4);
// weights (16 outs x 4 d) register-resident. Per token: 64 FMA + 2 DPP stages
// -> quad leaders dump 16 partials to LDS; per 4-token batch each wave
// transpose-reads one token (16 strided b32 + 2 DPP) -> logits LDS.
// ---------------------------------------------------------------------------
__global__ __launch_bounds__(256) void kA(const float* __restrict__ x,
    const float* __restrict__ wg, const float* __restrict__ wn,
    const float* __restrict__ nz, int* __restrict__ eid, float* __restrict__ part) {
  __shared__ float pd[4][64][20];   // [batch-token][quad][16 outs + pad]
  __shared__ float lgS[16][17];     // final logits per token
  int t = threadIdx.x;
  int n0 = blockIdx.x << 4;
  int qd = t >> 2, l2 = t & 3, wid = t >> 6, lane = t & 63;
  const float* wgp = wg + (size_t)(t << 2) * NE;
  const float* wnp = wn + (size_t)(t << 2) * NE;
  float4 g0a = *(const float4*)(wgp + 0),  g0b = *(const float4*)(wgp + 4);
  float4 g1a = *(const float4*)(wgp + 8),  g1b = *(const float4*)(wgp + 12);
  float4 g2a = *(const float4*)(wgp + 16), g2b = *(const float4*)(wgp + 20);
  float4 g3a = *(const float4*)(wgp + 24), g3b = *(const float4*)(wgp + 28);
  float4 q0a = *(const float4*)(wnp + 0),  q0b = *(const float4*)(wnp + 4);
  float4 q1a = *(const float4*)(wnp + 8),  q1b = *(const float4*)(wnp + 12);
  float4 q2a = *(const float4*)(wnp + 16), q2b = *(const float4*)(wnp + 20);
  float4 q3a = *(const float4*)(wnp + 24), q3b = *(const float4*)(wnp + 28);
  const float* xb = x + (size_t)n0 * DIM + (t << 2);

  float4 xc0 = *(const float4*)(xb + 0 * DIM);
  float4 xc1 = *(const float4*)(xb + 1 * DIM);
  float4 xc2 = *(const float4*)(xb + 2 * DIM);
  float4 xc3 = *(const float4*)(xb + 3 * DIM);
  #pragma unroll
  for (int b = 0; b < 4; ++b) {
    float4 xn0, xn1, xn2, xn3;
    if (b < 3) {
      const float* xbn = xb + (size_t)((b + 1) << 2) * DIM;
      xn0 = *(const float4*)(xbn + 0 * DIM);
      xn1 = *(const float4*)(xbn + 1 * DIM);
      xn2 = *(const float4*)(xbn + 2 * DIM);
      xn3 = *(const float4*)(xbn + 3 * DIM);
    }
    #define TOKEN(K, XC) { \
      float4 aA = Z4, aB = Z4, aC = Z4, aD = Z4; \
      FMA4(aA, (XC).x, g0a); FMA4(aB, (XC).x, g0b); FMA4(aC, (XC).x, q0a); FMA4(aD, (XC).x, q0b); \
      FMA4(aA, (XC).y, g1a); FMA4(aB, (XC).y, g1b); FMA4(aC, (XC).y, q1a); FMA4(aD, (XC).y, q1b); \
      FMA4(aA, (XC).z, g2a); FMA4(aB, (XC).z, g2b); FMA4(aC, (XC).z, q2a); FMA4(aD, (XC).z, q2b); \
      FMA4(aA, (XC).w, g3a); FMA4(aB, (XC).w, g3b); FMA4(aC, (XC).w, q3a); FMA4(aD, (XC).w, q3b); \
      QRED4(aA); QRED4(aB); QRED4(aC); QRED4(aD); \
      if (l2 == 0) { \
        *(float4*)&pd[K][qd][0]  = aA; *(float4*)&pd[K][qd][4]  = aB; \
        *(float4*)&pd[K][qd][8]  = aC; *(float4*)&pd[K][qd][12] = aD; } }
    TOKEN(0, xc0) TOKEN(1, xc1) TOKEN(2, xc2) TOKEN(3, xc3)
    #undef TOKEN
    __syncthreads();
    { // wave `wid` reduces batch token `wid`: sum 64 quads for output o
      int o = lane >> 2, r2 = lane & 3;
      float s = 0.f;
      #pragma unroll
      for (int j = 0; j < 16; ++j) s += pd[wid][(j << 2) + r2][o];
      s = DPP_ADD(s, 0xB1); s = DPP_ADD(s, 0x4E);
      if (r2 == 0) lgS[(b << 2) + wid][o] = s;
    }
    __syncthreads();
    if (b < 3) { xc0 = xn0; xc1 = xn1; xc2 = xn2; xc3 = xn3; }
  }
  if (t < 16) {
    int n = n0 + t;
    float cl[8], st[8], lg[8];
    #pragma unroll
    for (int e = 0; e < 8; ++e) cl[e] = lgS[t][e];
    #pragma unroll
    for (int e = 0; e < 8; ++e) {
      st[e] = softplusf(lgS[t][8 + e]) + 0.01f;
      lg[e] = fmaf(nz[(size_t)n * NE + e], st[e], cl[e]);
    }
    float m1 = -1e30f, m2 = -1e30f; int idx = 0;
    #pragma unroll
    for (int e = 0; e < 8; ++e) {
      float v = lg[e];
      if (v > m1)      { m2 = m1; m1 = v; idx = e; }
      else if (v > m2) { m2 = v; }
    }
    eid[n] = idx;
    float pr[8], cw[8];
    #pragma unroll
    for (int e = 0; e < 8; ++e) {
      float thr = (lg[e] > m2) ? m2 : m1;
      pr[e] = ncdf((cl[e] - thr) / st[e]);
    }
    #pragma unroll
    for (int e = 0; e < 8; ++e) cw[e] = (float)__popcll(__ballot(idx == e));
    #pragma unroll
    for (int e = 0; e < 8; ++e) {
      #pragma unroll
      for (int off = 1; off <= 8; off <<= 1) pr[e] += __shfl_xor(pr[e], off);
    }
    if (t == 0) {
      #pragma unroll
      for (int e = 0; e < 8; ++e) {
        part[blockIdx.x * 16 + e]     = cw[e];
        part[blockIdx.x * 16 + 8 + e] = pr[e];
      }
    }
  }
}

// ---------------------------------------------------------------------------
// Kernel B: reduce 512x16 partials -> importance[8], load[8]; counts; fill=0.
// ---------------------------------------------------------------------------
__global__ __launch_bounds__(256) void kB(const float* __restrict__ part,
    float* __restrict__ outIL, int* __restrict__ counts, int* __restrict__ fill) {
  __shared__ float red[16][16];
  int t = threadIdx.x;
  int s = t & 15, g = t >> 4;
  float sum = 0.f;
  for (int j = 0; j < 32; ++j) sum += part[(g + 16 * j) * 16 + s];
  red[g][s] = sum;
  __syncthreads();
  if (t < 16) {
    float tot = 0.f;
    #pragma unroll
    for (int gg = 0; gg < 16; ++gg) tot += red[gg][t];
    outIL[t] = tot;
    if (t < 8) { counts[t] = (int)(tot + 0.5f); fill[t] = 0; }
  }
}

// ---------------------------------------------------------------------------
// Kernel C: bucket tokens by expert (LDS hist + 8 global atomics per block).
// ---------------------------------------------------------------------------
__global__ __launch_bounds__(256) void kC(const int* __restrict__ eid,
    const int* __restrict__ counts, int* __restrict__ fill, int* __restrict__ bucket) {
  __shared__ int lcnt[8], lbase[8];
  int t = threadIdx.x;
  if (t < 8) lcnt[t] = 0;
  __syncthreads();
  int n = blockIdx.x * 256 + t;
  int e = eid[n];
  int rank = atomicAdd(&lcnt[e], 1);
  __syncthreads();
  if (t < 8) lbase[t] = atomicAdd(&fill[t], lcnt[t]);
  __syncthreads();
  int off = 0;
  #pragma unroll
  for (int i = 0; i < 8; ++i) if (i < e) off += counts[i];
  bucket[off + lbase[e] + rank] = n;
}

// ---------------------------------------------------------------------------
// Kernel D: h_sorted[p] = lora_a[e] @ x[bucket[p]], 16 tokens/tile.
// Same structure as kA: thread owns 4 d, 16 r-rows register-resident
// (float4 along d), DPP quad-reduce + LDS transpose-dump.
// ---------------------------------------------------------------------------
__global__ __launch_bounds__(256) void kD(const float* __restrict__ x,
    const float* __restrict__ la, const int* __restrict__ counts,
    const int* __restrict__ bucket, float* __restrict__ h) {
  __shared__ float pd[4][64][20];
  __shared__ float hS[16][17];
  __shared__ int toks[16];
  int tile = blockIdx.x;
  int e = -1, jt = 0, off = 0;
  { int tot = 0, o = 0;
    #pragma unroll
    for (int i = 0; i < 8; ++i) {
      int c = counts[i]; int nt = (c + 15) >> 4;
      if (e < 0 && tile < tot + nt) { e = i; jt = tile - tot; off = o; }
      tot += nt; o += c;
    } }
  if (e < 0) return;
  int cnt = counts[e];
  int p0 = off + (jt << 4);
  int valid = min(16, cnt - (jt << 4));
  int t = threadIdx.x;
  if (t < 16) toks[t] = bucket[p0 + min(t, valid - 1)];
  __syncthreads();
  int qd = t >> 2, l2 = t & 3, wid = t >> 6, lane = t & 63;
  const float* ap = la + (size_t)e * NR * DIM + (t << 2);
  float4 w0  = *(const float4*)(ap + 0  * DIM), w1  = *(const float4*)(ap + 1  * DIM);
  float4 w2  = *(const float4*)(ap + 2  * DIM), w3  = *(const float4*)(ap + 3  * DIM);
  float4 w4  = *(const float4*)(ap + 4  * DIM), w5  = *(const float4*)(ap + 5  * DIM);
  float4 w6  = *(const float4*)(ap + 6  * DIM), w7  = *(const float4*)(ap + 7  * DIM);
  float4 w8  = *(const float4*)(ap + 8  * DIM), w9  = *(const float4*)(ap + 9  * DIM);
  float4 w10 = *(const float4*)(ap + 10 * DIM), w11 = *(const float4*)(ap + 11 * DIM);
  float4 w12 = *(const float4*)(ap + 12 * DIM), w13 = *(const float4*)(ap + 13 * DIM);
  float4 w14 = *(const float4*)(ap + 14 * DIM), w15 = *(const float4*)(ap + 15 * DIM);
  int dof = t << 2;
  float4 xc0 = *(const float4*)(x + (size_t)toks[0] * DIM + dof);
  float4 xc1 = *(const float4*)(x + (size_t)toks[1] * DIM + dof);
  float4 xc2 = *(const float4*)(x + (size_t)toks[2] * DIM + dof);
  float4 xc3 = *(const float4*)(x + (size_t)toks[3] * DIM + dof);
  #pragma unroll
  for (int b = 0; b < 4; ++b) {
    float4 xn0, xn1, xn2, xn3;
    if (b < 3) {
      int tb4 = (b + 1) << 2;
      xn0 = *(const float4*)(x + (size_t)toks[tb4 + 0] * DIM + dof);
      xn1 = *(const float4*)(x + (size_t)toks[tb4 + 1] * DIM + dof);
      xn2 = *(const float4*)(x + (size_t)toks[tb4 + 2] * DIM + dof);
      xn3 = *(const float4*)(x + (size_t)toks[tb4 + 3] * DIM + dof);
    }
    #define DOTC(ACC, W, XC) ACC = fmaf((XC).x,(W).x, fmaf((XC).y,(W).y, fmaf((XC).z,(W).z, fmaf((XC).w,(W).w,(ACC)))))
    #define TOKEN(K, XC) { \
      float4 aA = Z4, aB = Z4, aC = Z4, aD = Z4; \
      DOTC(aA.x, w0, XC);  DOTC(aA.y, w1, XC);  DOTC(aA.z, w2, XC);  DOTC(aA.w, w3, XC); \
      DOTC(aB.x, w4, XC);  DOTC(aB.y, w5, XC);  DOTC(aB.z, w6, XC);  DOTC(aB.w, w7, XC); \
      DOTC(aC.x, w8, XC);  DOTC(aC.y, w9, XC);  DOTC(aC.z, w10, XC); DOTC(aC.w, w11, XC); \
      DOTC(aD.x, w12, XC); DOTC(aD.y, w13, XC); DOTC(aD.z, w14, XC); DOTC(aD.w, w15, XC); \
      QRED4(aA); QRED4(aB); QRED4(aC); QRED4(aD); \
      if (l2 == 0) { \
        *(float4*)&pd[K][qd][0]  = aA; *(float4*)&pd[K][qd][4]  = aB; \
        *(float4*)&pd[K][qd][8]  = aC; *(float4*)&pd[K][qd][12] = aD; } }
    TOKEN(0, xc0) TOKEN(1, xc1) TOKEN(2, xc2) TOKEN(3, xc3)
    #undef TOKEN
    #undef DOTC
    __syncthreads();
    { int o = lane >> 2, r2 = lane & 3;
      float s = 0.f;
      #pragma unroll
      for (int j = 0; j < 16; ++j) s += pd[wid][(j << 2) + r2][o];
      s = DPP_ADD(s, 0xB1); s = DPP_ADD(s, 0x4E);
      if (r2 == 0) hS[(b << 2) + wid][o] = s;
    }
    __syncthreads();
    if (b < 3) { xc0 = xn0; xc1 = xn1; xc2 = xn2; xc3 = xn3; }
  }
  if (t < 64) {
    int tok = t >> 2, rq = (t & 3) << 2;
    if (tok < valid) {
      float4 v = make_float4(hS[tok][rq + 0], hS[tok][rq + 1], hS[tok][rq + 2], hS[tok][rq + 3]);
      *(float4*)(h + (size_t)(p0 + tok) * NR + rq) = v;
    }
  }
}

// ---------------------------------------------------------------------------
// Kernel E: out[n] = lora_b[e] @ h. Tiles: 64 tokens x 256 outs.
// ---------------------------------------------------------------------------
__global__ __launch_bounds__(256) void kE(const float* __restrict__ h,
    const float* __restrict__ lb, const int* __restrict__ counts,
    const int* __restrict__ bucket, float* __restrict__ out) {
  __shared__ float bt[16][260];
  __shared__ float ht[16][64];
  __shared__ int toks[64];
  int tile = blockIdx.y;
  int e = -1, jt = 0, off = 0;
  { int tot = 0, o = 0;
    #pragma unroll
    for (int i = 0; i < 8; ++i) {
      int c = counts[i]; int nt = (c + 63) >> 6;
      if (e < 0 && tile < tot + nt) { e = i; jt = tile - tot; off = o; }
      tot += nt; o += c;
    } }
  if (e < 0) return;
  int cnt = counts[e];
  int p0 = off + (jt << 6);
  int valid = min(64, cnt - (jt << 6));
  int o0 = blockIdx.x << 8;
  int t = threadIdx.x;
  if (t < 64) toks[t] = bucket[p0 + min(t, valid - 1)];
  const float* bbase = lb + ((size_t)e * NO + o0) * NR;
  #pragma unroll
  for (int kk = 0; kk < 4; ++kk) {
    int idx = (kk << 8) + t;
    int o = idx >> 2, rq = (idx & 3) << 2;
    float4 v = *(const float4*)(bbase + o * NR + rq);
    bt[rq + 0][o] = v.x; bt[rq + 1][o] = v.y; bt[rq + 2][o] = v.z; bt[rq + 3][o] = v.w;
  }
  { int tok = t >> 2, rq = (t & 3) << 2;
    float4 v = *(const float4*)(h + (size_t)(p0 + min(tok, valid - 1)) * NR + rq);
    ht[rq + 0][tok] = v.x; ht[rq + 1][tok] = v.y; ht[rq + 2][tok] = v.z; ht[rq + 3][tok] = v.w; }
  __syncthreads();
  int og = t & 31, tokg = t >> 5;
  int ob = og << 2, tb = tokg << 3;
  float4 z = Z4;
  float4 aL0=z,aL1=z,aL2=z,aL3=z,aL4=z,aL5=z,aL6=z,aL7=z;
  float4 aH0=z,aH1=z,aH2=z,aH3=z,aH4=z,aH5=z,aH6=z,aH7=z;
  #pragma unroll
  for (int r = 0; r < 16; ++r) {
    float4 blo = *(const float4*)&bt[r][ob];
    float4 bhi = *(const float4*)&bt[r][ob + 128];
    float4 h0  = *(const float4*)&ht[r][tb];
    float4 h1  = *(const float4*)&ht[r][tb + 4];
    FMA4(aL0, h0.x, blo); FMA4(aH0, h0.x, bhi);
    FMA4(aL1, h0.y, blo); FMA4(aH1, h0.y, bhi);
    FMA4(aL2, h0.z, blo); FMA4(aH2, h0.z, bhi);
    FMA4(aL3, h0.w, blo); FMA4(aH3, h0.w, bhi);
    FMA4(aL4, h1.x, blo); FMA4(aH4, h1.x, bhi);
    FMA4(aL5, h1.y, blo); FMA4(aH5, h1.y, bhi);
    FMA4(aL6, h1.z, blo); FMA4(aH6, h1.z, bhi);
    FMA4(aL7, h1.w, blo); FMA4(aH7, h1.w, bhi);
  }
  #define ST(J, AL, AH) { int tt = tb + (J); if (tt < valid) { \
      float* p = out + (size_t)toks[tt] * NO + o0 + ob; \
      *(float4*)p = AL; *(float4*)(p + 128) = AH; } }
  ST(0, aL0, aH0); ST(1, aL1, aH1); ST(2, aL2, aH2); ST(3, aL3, aH3);
  ST(4, aL4, aH4); ST(5, aL5, aH5); ST(6, aL6, aH6); ST(7, aL7, aH7);
  #undef ST
}

// ---------------------------------------------------------------------------
extern "C" void kernel_launch(void* const* d_in, const int* in_sizes, int n_in,
                              void* d_out, int out_size, void* d_ws, size_t ws_size,
                              hipStream_t stream) {
  const float* x  = (const float*)d_in[0];
  const float* wg = (const float*)d_in[1];
  const float* wn = (const float*)d_in[2];
  const float* la = (const float*)d_in[3];
  const float* lb = (const float*)d_in[4];
  const float* nz = (const float*)d_in[5];
  float* out = (float*)d_out;

  char* ws = (char*)d_ws;
  float* h        = (float*)(ws);                 // 524288 B
  int*   eid      = (int*)  (ws + 524288);        // 32768 B
  int*   bucket   = (int*)  (ws + 557056);        // 32768 B
  float* partials = (float*)(ws + 589824);        // 32768 B
  int*   counts   = (int*)  (ws + 622592);        // 32 B
  int*   fill     = (int*)  (ws + 622624);        // 32 B

  kA<<<512, 256, 0, stream>>>(x, wg, wn, nz, eid, partials);
  kB<<<1, 256, 0, stream>>>(partials, out + OUT_ELEMS, counts, fill);
  kC<<<32, 256, 0, stream>>>(eid, counts, fill, bucket);
  kD<<<519, 256, 0, stream>>>(x, la, counts, bucket, h);
  kE<<<dim3(12, 135), 256, 0, stream>>>(h, lb, counts, bucket, out);
}